// Round 1
// 214.425 us; speedup vs baseline: 1.1973x; 1.1973x over previous
//
#include <hip/hip_runtime.h>
#include <stdint.h>

#define Mdim 8192
#define Ndim 4096
#define Kdim 2048
#define Hdim 1024

typedef __attribute__((ext_vector_type(8))) short bf16x8;
typedef __attribute__((ext_vector_type(4))) float f32x4;

__device__ __forceinline__ unsigned short f2bf(float f) {
  union { float f; unsigned u; } v; v.f = f;
  unsigned u = v.u + 0x7fffu + ((v.u >> 16) & 1u);
  return (unsigned short)(u >> 16);
}
__device__ __forceinline__ float bf2f(unsigned short s) {
  union { unsigned u; float f; } v; v.u = ((unsigned)s) << 16;
  return v.f;
}
__device__ __forceinline__ float sigmoidf_(float x) { return 1.f / (1.f + __expf(-x)); }
__device__ __forceinline__ float tanhf_(float x) { return 1.f - 2.f / (1.f + __expf(2.f * x)); }

// ---------- pack [x | h] into bf16 A[M][K] ----------
__global__ void conv_a_kernel(const float* __restrict__ x, const float* __restrict__ h,
                              unsigned short* __restrict__ A) {
  int idx = blockIdx.x * 256 + threadIdx.x;   // one 8-elem chunk each
  int m = idx >> 8;                           // 2048/8 = 256 chunks per row
  int k = (idx & 255) * 8;
  const float* src = (k < Hdim) ? (x + (size_t)m * Hdim + k)
                                : (h + (size_t)m * Hdim + (k - Hdim));
  float4 a = ((const float4*)src)[0];
  float4 b = ((const float4*)src)[1];
  union { unsigned short s[8]; int4 v; } o;
  o.s[0] = f2bf(a.x); o.s[1] = f2bf(a.y); o.s[2] = f2bf(a.z); o.s[3] = f2bf(a.w);
  o.s[4] = f2bf(b.x); o.s[5] = f2bf(b.y); o.s[6] = f2bf(b.z); o.s[7] = f2bf(b.w);
  *(int4*)(A + (size_t)idx * 8) = o.v;
}

// ---------- transpose [W_xh ; W_hh] (K x N) into bf16 Wt[N][K] ----------
__global__ void conv_w_kernel(const float* __restrict__ Wxh, const float* __restrict__ Whh,
                              unsigned short* __restrict__ Wt) {
  __shared__ float tile[32][33];
  int k0 = blockIdx.x * 32;
  int n0 = blockIdx.y * 32;
  int tx = threadIdx.x & 31, ty = threadIdx.x >> 5;  // 32 x 8
#pragma unroll
  for (int i = 0; i < 32; i += 8) {
    int k = k0 + ty + i;
    float v = (k < Hdim) ? Wxh[(size_t)k * Ndim + n0 + tx]
                         : Whh[(size_t)(k - Hdim) * Ndim + n0 + tx];
    tile[ty + i][tx] = v;
  }
  __syncthreads();
#pragma unroll
  for (int i = 0; i < 32; i += 8) {
    int n = n0 + ty + i;
    Wt[(size_t)n * Kdim + k0 + tx] = f2bf(tile[tx][ty + i]);
  }
}

// ---------- GEMM: C[M][N] (bf16) = A[M][K] * Wt[N][K]^T ----------
// 256x256 tile, BK=64, 8 waves (2M x 4N), 8-phase schedule with counted vmcnt.
#define BM 256
#define BN 256
#define BK 64
#define NT (Kdim / BK)   // 32

__global__ __launch_bounds__(512, 2)
void gemm_kernel(const unsigned short* __restrict__ A, const unsigned short* __restrict__ Bt,
                 unsigned short* __restrict__ C) {
  // [dbuf][A/B][256 rows x 64 bf16] = 128 KiB
  __shared__ unsigned short lds[2][2][BM * BK];
  const int tid = threadIdx.x;
  int bid = blockIdx.x;
  int id = (bid & 7) * 64 + (bid >> 3);      // XCD swizzle (512 % 8 == 0, bijective)
  int mT = id >> 4, nT = id & 15;            // 32 x 16 tiles
  size_t m0 = (size_t)mT * BM, n0 = (size_t)nT * BN;
  const int lane = tid & 63, w = tid >> 6;
  const int wm = w >> 2, wn = w & 3;         // 2x4 waves -> 128x64 output each
  const int r16 = lane & 15, q = lane >> 4;

  const unsigned short* gA = A + m0 * Kdim;
  const unsigned short* gB = Bt + n0 * Kdim;

  // stage one half-tile (region: 0=A rows0-127, 1=A rows128-255, 2=B0, 3=B1).
  // LDS dest is linear (wave-uniform base + lane*16); the slot swizzle
  // stored_slot = logical_slot ^ (row&7) is applied on the GLOBAL source.
  auto stage = [&](int b, int kt, int region) {
    const int mat = region >> 1, half = region & 1;
    const unsigned short* g = mat ? gB : gA;
#pragma unroll
    for (int it = 0; it < 2; ++it) {
      int c = it * 512 + tid;                // 1024 chunks of 16 B per half-tile
      int rr = c >> 3, ss = c & 7;
      __builtin_amdgcn_global_load_lds(
          (const __attribute__((address_space(1))) void*)(
              g + (size_t)(half * 128 + rr) * Kdim + kt * BK + ((ss ^ (rr & 7)) << 3)),
          (__attribute__((address_space(3))) void*)(&lds[b][mat][half * (128 * BK) + c * 8]),
          16, 0, 0);
    }
  };

  f32x4 acc[8][4] = {};
  bf16x8 av0[4][2], av1[4][2], bv0[2][2], bv1[2][2];

  auto readA = [&](int cur, int mh, bf16x8 (&av)[4][2]) {
#pragma unroll
    for (int mi = 0; mi < 4; ++mi) {
      int lr = wm * 128 + mh * 64 + mi * 16 + r16;
      const unsigned short* base = &lds[cur][0][lr * BK];
#pragma unroll
      for (int ks = 0; ks < 2; ++ks)
        av[mi][ks] = *(const bf16x8*)(base + ((((ks << 2) | q) ^ (lr & 7)) << 3));
    }
  };
  auto readB = [&](int cur, int nh, bf16x8 (&bv)[2][2]) {
#pragma unroll
    for (int ni = 0; ni < 2; ++ni) {
      int lr = wn * 64 + nh * 32 + ni * 16 + r16;
      const unsigned short* base = &lds[cur][1][lr * BK];
#pragma unroll
      for (int ks = 0; ks < 2; ++ks)
        bv[ni][ks] = *(const bf16x8*)(base + ((((ks << 2) | q) ^ (lr & 7)) << 3));
    }
  };

  // one C-quadrant over full K=64: 16 MFMA, setprio-wrapped (T5)
#define QUAD(AV, BV, MI0, NI0)                                                        \
  do {                                                                                \
    __builtin_amdgcn_s_setprio(1);                                                    \
    _Pragma("unroll") for (int mi = 0; mi < 4; ++mi)                                  \
      _Pragma("unroll") for (int ni = 0; ni < 2; ++ni)                                \
        _Pragma("unroll") for (int ks = 0; ks < 2; ++ks)                              \
          acc[(MI0) + mi][(NI0) + ni] = __builtin_amdgcn_mfma_f32_16x16x32_bf16(      \
              AV[mi][ks], BV[ni][ks], acc[(MI0) + mi][(NI0) + ni], 0, 0, 0);          \
    __builtin_amdgcn_s_setprio(0);                                                    \
  } while (0)

  // prologue: 6 half-tiles in flight, then wait for K-tile 0 (4 halves)
  stage(0, 0, 0); stage(0, 0, 1); stage(0, 0, 2); stage(0, 0, 3);
  stage(1, 1, 0); stage(1, 1, 1);
  asm volatile("s_waitcnt vmcnt(4)" ::: "memory");
  __builtin_amdgcn_s_barrier();

  // main loop: stages of t+1 (B halves) and t+2 (A halves); vmcnt(4) once per K-tile.
  // WAR safety: A regions of buf[cur] are fully consumed by end of P2 (reads in
  // P1/P2, lgkm-drained before each MFMA, barrier-separated); B regions of
  // buf[nxt] were last read in K-tile t-1's P3.
#pragma unroll 2
  for (int t = 0; t < NT - 2; ++t) {
    int cur = t & 1, nxt = cur ^ 1;
    // P1: reads av0 (8) + bv0 (4); stages B0(t+1)
    readA(cur, 0, av0);
    readB(cur, 0, bv0);
    stage(nxt, t + 1, 2);
    __builtin_amdgcn_s_barrier();
    QUAD(av0, bv0, 0, 0);
    __builtin_amdgcn_s_barrier();
    // P2: reads av1 (8); stages B1(t+1)
    readA(cur, 1, av1);
    stage(nxt, t + 1, 3);
    __builtin_amdgcn_s_barrier();
    QUAD(av1, bv0, 4, 0);
    __builtin_amdgcn_s_barrier();
    // P3: reads bv1 (4); stages A0(t+2) into the live buffer (A reads done at P2)
    readB(cur, 1, bv1);
    stage(cur, t + 2, 0);
    __builtin_amdgcn_s_barrier();
    QUAD(av1, bv1, 4, 2);
    __builtin_amdgcn_s_barrier();
    // P4: stages A1(t+2); counted wait — leaves A0/A1(t+2) (4 loads) in flight
    stage(cur, t + 2, 1);
    asm volatile("s_waitcnt vmcnt(4)" ::: "memory");
    __builtin_amdgcn_s_barrier();
    QUAD(av0, bv1, 0, 2);
    __builtin_amdgcn_s_barrier();
  }
  // t = NT-2: no t+2 to stage; drain fully for the last K-tile
  {
    const int cur = (NT - 2) & 1, nxt = cur ^ 1;
    readA(cur, 0, av0);
    readB(cur, 0, bv0);
    stage(nxt, NT - 1, 2);
    __builtin_amdgcn_s_barrier();
    QUAD(av0, bv0, 0, 0);
    __builtin_amdgcn_s_barrier();
    readA(cur, 1, av1);
    stage(nxt, NT - 1, 3);
    __builtin_amdgcn_s_barrier();
    QUAD(av1, bv0, 4, 0);
    __builtin_amdgcn_s_barrier();
    readB(cur, 1, bv1);
    __builtin_amdgcn_s_barrier();
    QUAD(av1, bv1, 4, 2);
    __builtin_amdgcn_s_barrier();
    asm volatile("s_waitcnt vmcnt(0)" ::: "memory");
    __builtin_amdgcn_s_barrier();
    QUAD(av0, bv1, 0, 2);
    __builtin_amdgcn_s_barrier();
  }
  // t = NT-1: all data resident, no stages -> no barriers needed
  {
    const int cur = (NT - 1) & 1;
    readA(cur, 0, av0);
    readB(cur, 0, bv0);
    QUAD(av0, bv0, 0, 0);
    readA(cur, 1, av1);
    QUAD(av1, bv0, 4, 0);
    readB(cur, 1, bv1);
    QUAD(av1, bv1, 4, 2);
    QUAD(av0, bv1, 0, 2);
  }
#undef QUAD

  // epilogue: D layout col = lane&15, row = (lane>>4)*4 + j
#pragma unroll
  for (int mi = 0; mi < 8; ++mi) {
#pragma unroll
    for (int ni = 0; ni < 4; ++ni) {
      size_t row = m0 + wm * 128 + mi * 16 + q * 4;
      size_t col = n0 + wn * 64 + ni * 16 + r16;
#pragma unroll
      for (int j = 0; j < 4; ++j)
        C[(row + j) * Ndim + col] = f2bf(acc[mi][ni][j]);
    }
  }
}

// ---------- tail: bias + group LN + gates + c LN + outputs ----------
__global__ __launch_bounds__(256)
void tail_kernel(const unsigned short* __restrict__ Cc, const float* __restrict__ cin,
                 const float* __restrict__ bias, const float* __restrict__ gamma,
                 const float* __restrict__ beta, const float* __restrict__ cg,
                 const float* __restrict__ cb, float* __restrict__ out) {
  int lane = threadIdx.x & 63;
  int wid = threadIdx.x >> 6;
  int row = blockIdx.x * 4 + wid;     // one wave per row
  const int base = lane * 16;         // 16 columns per lane

  // c values
  const float4* cp = (const float4*)(cin + (size_t)row * Hdim + base);
  float4 c0 = cp[0], c1 = cp[1], c2 = cp[2], c3 = cp[3];
  float cv[16] = {c0.x, c0.y, c0.z, c0.w, c1.x, c1.y, c1.z, c1.w,
                  c2.x, c2.y, c2.z, c2.w, c3.x, c3.y, c3.z, c3.w};

  float accv[16];   // running sig(i)*tanh(j), then new_c
  float ov[16];     // sig(o)

#pragma unroll
  for (int g = 0; g < 4; ++g) {
    const int4* pp = (const int4*)(Cc + (size_t)row * Ndim + g * Hdim + base);
    int4 u0 = pp[0], u1 = pp[1];
    float vals[16];
    {
      int uu[8] = {u0.x, u0.y, u0.z, u0.w, u1.x, u1.y, u1.z, u1.w};
#pragma unroll
      for (int i = 0; i < 8; ++i) {
        vals[2 * i]     = bf2f((unsigned short)(uu[i] & 0xffff));
        vals[2 * i + 1] = bf2f((unsigned short)(((unsigned)uu[i]) >> 16));
      }
    }
    const float* bp = bias + g * Hdim + base;
#pragma unroll
    for (int t = 0; t < 16; ++t) vals[t] += bp[t];
    float s = 0.f, ss = 0.f;
#pragma unroll
    for (int t = 0; t < 16; ++t) { s += vals[t]; ss += vals[t] * vals[t]; }
#pragma unroll
    for (int off = 32; off; off >>= 1) { s += __shfl_xor(s, off); ss += __shfl_xor(ss, off); }
    float mean = s * (1.f / 1024.f);
    float rstd = rsqrtf(ss * (1.f / 1024.f) - mean * mean + 1e-3f);
    const float* gp = gamma + g * Hdim + base;
    const float* bb = beta + g * Hdim + base;
    if (g == 0) {
#pragma unroll
      for (int t = 0; t < 16; ++t)
        accv[t] = sigmoidf_((vals[t] - mean) * rstd * gp[t] + bb[t]);
    } else if (g == 1) {
#pragma unroll
      for (int t = 0; t < 16; ++t)
        accv[t] *= tanhf_((vals[t] - mean) * rstd * gp[t] + bb[t]);
    } else if (g == 2) {
#pragma unroll
      for (int t = 0; t < 16; ++t)
        accv[t] = cv[t] * sigmoidf_((vals[t] - mean) * rstd * gp[t] + bb[t] + 1.f) + accv[t];
    } else {
#pragma unroll
      for (int t = 0; t < 16; ++t)
        ov[t] = sigmoidf_((vals[t] - mean) * rstd * gp[t] + bb[t]);
    }
  }

  // LN over new_c (accv)
  float s = 0.f, ss = 0.f;
#pragma unroll
  for (int t = 0; t < 16; ++t) { s += accv[t]; ss += accv[t] * accv[t]; }
#pragma unroll
  for (int off = 32; off; off >>= 1) { s += __shfl_xor(s, off); ss += __shfl_xor(ss, off); }
  float mean = s * (1.f / 1024.f);
  float rstd = rsqrtf(ss * (1.f / 1024.f) - mean * mean + 1e-3f);

  const float* cgp = cg + base;
  const float* cbp = cb + base;
  float hv[16];
#pragma unroll
  for (int t = 0; t < 16; ++t) {
    float cl = (accv[t] - mean) * rstd * cgp[t] + cbp[t];
    hv[t] = tanhf_(cl) * ov[t];
  }

  float4* oh = (float4*)(out + (size_t)row * Hdim + base);
  float4* oc = (float4*)(out + (size_t)Mdim * Hdim + (size_t)row * Hdim + base);
#pragma unroll
  for (int v = 0; v < 4; ++v) {
    oh[v] = make_float4(hv[4 * v], hv[4 * v + 1], hv[4 * v + 2], hv[4 * v + 3]);
    oc[v] = make_float4(accv[4 * v], accv[4 * v + 1], accv[4 * v + 2], accv[4 * v + 3]);
  }
}

extern "C" void kernel_launch(void* const* d_in, const int* in_sizes, int n_in,
                              void* d_out, int out_size, void* d_ws, size_t ws_size,
                              hipStream_t stream) {
  const float* x    = (const float*)d_in[0];
  const float* c    = (const float*)d_in[1];
  const float* h    = (const float*)d_in[2];
  const float* Wxh  = (const float*)d_in[3];
  const float* Whh  = (const float*)d_in[4];
  const float* bias = (const float*)d_in[5];
  const float* lng  = (const float*)d_in[6];
  const float* lnb  = (const float*)d_in[7];
  const float* cg   = (const float*)d_in[8];
  const float* cb   = (const float*)d_in[9];
  float* out = (float*)d_out;

  // workspace layout (needs 117,440,512 B):
  unsigned short* Abf = (unsigned short*)d_ws;                  // 8192*2048 bf16 = 32 MiB
  unsigned short* Wt  = Abf + (size_t)Mdim * Kdim;              // 4096*2048 bf16 = 16 MiB
  unsigned short* Cc  = Wt  + (size_t)Ndim * Kdim;              // 8192*4096 bf16 = 64 MiB

  conv_a_kernel<<<8192, 256, 0, stream>>>(x, h, Abf);
  conv_w_kernel<<<dim3(Kdim / 32, Ndim / 32), 256, 0, stream>>>(Wxh, Whh, Wt);
  gemm_kernel<<<(Mdim / BM) * (Ndim / BN), 512, 0, stream>>>(Abf, Wt, Cc);
  tail_kernel<<<Mdim / 4, 256, 0, stream>>>(Cc, c, bias, lng, lnb, cg, cb, out);
}

// Round 2
// 209.462 us; speedup vs baseline: 1.2257x; 1.0237x over previous
//
#include <hip/hip_runtime.h>
#include <stdint.h>

#define Mdim 8192
#define Ndim 4096
#define Kdim 2048
#define Hdim 1024

typedef __attribute__((ext_vector_type(8))) short bf16x8;
typedef __attribute__((ext_vector_type(4))) float f32x4;

__device__ __forceinline__ unsigned short f2bf(float f) {
  union { float f; unsigned u; } v; v.f = f;
  unsigned u = v.u + 0x7fffu + ((v.u >> 16) & 1u);
  return (unsigned short)(u >> 16);
}
__device__ __forceinline__ float bf2f(unsigned short s) {
  union { unsigned u; float f; } v; v.u = ((unsigned)s) << 16;
  return v.f;
}
__device__ __forceinline__ float sigmoidf_(float x) { return 1.f / (1.f + __expf(-x)); }
__device__ __forceinline__ float tanhf_(float x) { return 1.f - 2.f / (1.f + __expf(2.f * x)); }

// ---------- pack [x | h] into bf16 A[M][K] ----------
__global__ void conv_a_kernel(const float* __restrict__ x, const float* __restrict__ h,
                              unsigned short* __restrict__ A) {
  int idx = blockIdx.x * 256 + threadIdx.x;   // one 8-elem chunk each
  int m = idx >> 8;                           // 2048/8 = 256 chunks per row
  int k = (idx & 255) * 8;
  const float* src = (k < Hdim) ? (x + (size_t)m * Hdim + k)
                                : (h + (size_t)m * Hdim + (k - Hdim));
  float4 a = ((const float4*)src)[0];
  float4 b = ((const float4*)src)[1];
  union { unsigned short s[8]; int4 v; } o;
  o.s[0] = f2bf(a.x); o.s[1] = f2bf(a.y); o.s[2] = f2bf(a.z); o.s[3] = f2bf(a.w);
  o.s[4] = f2bf(b.x); o.s[5] = f2bf(b.y); o.s[6] = f2bf(b.z); o.s[7] = f2bf(b.w);
  *(int4*)(A + (size_t)idx * 8) = o.v;
}

// ---------- transpose [W_xh ; W_hh] (K x N) into bf16 Wt[N][K] ----------
__global__ void conv_w_kernel(const float* __restrict__ Wxh, const float* __restrict__ Whh,
                              unsigned short* __restrict__ Wt) {
  __shared__ float tile[32][33];
  int k0 = blockIdx.x * 32;
  int n0 = blockIdx.y * 32;
  int tx = threadIdx.x & 31, ty = threadIdx.x >> 5;  // 32 x 8
#pragma unroll
  for (int i = 0; i < 32; i += 8) {
    int k = k0 + ty + i;
    float v = (k < Hdim) ? Wxh[(size_t)k * Ndim + n0 + tx]
                         : Whh[(size_t)(k - Hdim) * Ndim + n0 + tx];
    tile[ty + i][tx] = v;
  }
  __syncthreads();
#pragma unroll
  for (int i = 0; i < 32; i += 8) {
    int n = n0 + ty + i;
    Wt[(size_t)n * Kdim + k0 + tx] = f2bf(tile[tx][ty + i]);
  }
}

// ---------- GEMM: C[M][N] (bf16) = A[M][K] * Wt[N][K]^T ----------
// 256x256 tile, BK=64, 8 waves (2M x 4N), 8-phase schedule with counted vmcnt.
// v2: deepened prefetch — tile t+2 staged entirely during iter t (P3: A halves,
// P4: B halves), so tile t+1's loads get 4-5 phases of latency cover before the
// single per-K-tile vmcnt(8) drain (was 2-3 phases for the B halves).
#define BM 256
#define BN 256
#define BK 64
#define NT (Kdim / BK)   // 32

__global__ __launch_bounds__(512, 2)
void gemm_kernel(const unsigned short* __restrict__ A, const unsigned short* __restrict__ Bt,
                 unsigned short* __restrict__ C) {
  // [dbuf][A/B][256 rows x 64 bf16] = 128 KiB
  __shared__ unsigned short lds[2][2][BM * BK];
  const int tid = threadIdx.x;
  int bid = blockIdx.x;
  int id = (bid & 7) * 64 + (bid >> 3);      // XCD swizzle (512 % 8 == 0, bijective)
  int mT = id >> 4, nT = id & 15;            // 32 x 16 tiles
  size_t m0 = (size_t)mT * BM, n0 = (size_t)nT * BN;
  const int lane = tid & 63, w = tid >> 6;
  const int wm = w >> 2, wn = w & 3;         // 2x4 waves -> 128x64 output each
  const int r16 = lane & 15, q = lane >> 4;

  const unsigned short* gA = A + m0 * Kdim;
  const unsigned short* gB = Bt + n0 * Kdim;

  // stage one half-tile (region: 0=A rows0-127, 1=A rows128-255, 2=B0, 3=B1).
  // LDS dest is linear (wave-uniform base + lane*16); the slot swizzle
  // stored_slot = logical_slot ^ (row&7) is applied on the GLOBAL source.
  auto stage = [&](int b, int kt, int region) {
    const int mat = region >> 1, half = region & 1;
    const unsigned short* g = mat ? gB : gA;
#pragma unroll
    for (int it = 0; it < 2; ++it) {
      int c = it * 512 + tid;                // 1024 chunks of 16 B per half-tile
      int rr = c >> 3, ss = c & 7;
      __builtin_amdgcn_global_load_lds(
          (const __attribute__((address_space(1))) void*)(
              g + (size_t)(half * 128 + rr) * Kdim + kt * BK + ((ss ^ (rr & 7)) << 3)),
          (__attribute__((address_space(3))) void*)(&lds[b][mat][half * (128 * BK) + c * 8]),
          16, 0, 0);
    }
  };

  f32x4 acc[8][4] = {};
  bf16x8 av0[4][2], av1[4][2], bv0[2][2], bv1[2][2];

  auto readA = [&](int cur, int mh, bf16x8 (&av)[4][2]) {
#pragma unroll
    for (int mi = 0; mi < 4; ++mi) {
      int lr = wm * 128 + mh * 64 + mi * 16 + r16;
      const unsigned short* base = &lds[cur][0][lr * BK];
#pragma unroll
      for (int ks = 0; ks < 2; ++ks)
        av[mi][ks] = *(const bf16x8*)(base + ((((ks << 2) | q) ^ (lr & 7)) << 3));
    }
  };
  auto readB = [&](int cur, int nh, bf16x8 (&bv)[2][2]) {
#pragma unroll
    for (int ni = 0; ni < 2; ++ni) {
      int lr = wn * 64 + nh * 32 + ni * 16 + r16;
      const unsigned short* base = &lds[cur][1][lr * BK];
#pragma unroll
      for (int ks = 0; ks < 2; ++ks)
        bv[ni][ks] = *(const bf16x8*)(base + ((((ks << 2) | q) ^ (lr & 7)) << 3));
    }
  };

  // one C-quadrant over full K=64: 16 MFMA, setprio-wrapped (T5)
#define QUAD(AV, BV, MI0, NI0)                                                        \
  do {                                                                                \
    __builtin_amdgcn_s_setprio(1);                                                    \
    _Pragma("unroll") for (int mi = 0; mi < 4; ++mi)                                  \
      _Pragma("unroll") for (int ni = 0; ni < 2; ++ni)                                \
        _Pragma("unroll") for (int ks = 0; ks < 2; ++ks)                              \
          acc[(MI0) + mi][(NI0) + ni] = __builtin_amdgcn_mfma_f32_16x16x32_bf16(      \
              AV[mi][ks], BV[ni][ks], acc[(MI0) + mi][(NI0) + ni], 0, 0, 0);          \
    __builtin_amdgcn_s_setprio(0);                                                    \
  } while (0)

  // prologue: tiles 0 and 1 fully issued (16 loads); wait for tile 0 (8), keep
  // tile 1's 8 in flight. Invariant entering iter t: tile t resident, tile t+1
  // fully issued (8 outstanding).
  stage(0, 0, 0); stage(0, 0, 1); stage(0, 0, 2); stage(0, 0, 3);
  stage(1, 1, 0); stage(1, 1, 1); stage(1, 1, 2); stage(1, 1, 3);
  asm volatile("s_waitcnt vmcnt(8)" ::: "memory");
  __builtin_amdgcn_s_barrier();

  // main loop. WAR safety: A regions of buf[cur] fully consumed (lgkm-drained,
  // barrier-separated) by end of P2 -> staged with t+2 at P3; B regions by end
  // of P3 -> staged at P4. vmcnt(8) at P4 drains tile t+1 (issued iter t-1
  // P3/P4, 4-5 phases of latency cover), leaves tile t+2's 8 loads in flight.
#pragma unroll 2
  for (int t = 0; t < NT - 2; ++t) {
    int cur = t & 1;
    // P1: reads av0 (8) + bv0 (4)
    readA(cur, 0, av0);
    readB(cur, 0, bv0);
    __builtin_amdgcn_s_barrier();
    QUAD(av0, bv0, 0, 0);
    __builtin_amdgcn_s_barrier();
    // P2: reads av1 (8)
    readA(cur, 1, av1);
    __builtin_amdgcn_s_barrier();
    QUAD(av1, bv0, 4, 0);
    __builtin_amdgcn_s_barrier();
    // P3: reads bv1 (4); stages A0,A1(t+2) into cur (A reads done at P2)
    readB(cur, 1, bv1);
    stage(cur, t + 2, 0);
    stage(cur, t + 2, 1);
    __builtin_amdgcn_s_barrier();
    QUAD(av1, bv1, 4, 2);
    __builtin_amdgcn_s_barrier();
    // P4: stages B0,B1(t+2) (B reads done at P3); counted wait drains t+1
    stage(cur, t + 2, 2);
    stage(cur, t + 2, 3);
    asm volatile("s_waitcnt vmcnt(8)" ::: "memory");
    __builtin_amdgcn_s_barrier();
    QUAD(av0, bv1, 0, 2);
    __builtin_amdgcn_s_barrier();
  }
  // t = NT-2: nothing to stage; drain tile NT-1 fully
  {
    const int cur = (NT - 2) & 1;
    readA(cur, 0, av0);
    readB(cur, 0, bv0);
    __builtin_amdgcn_s_barrier();
    QUAD(av0, bv0, 0, 0);
    __builtin_amdgcn_s_barrier();
    readA(cur, 1, av1);
    __builtin_amdgcn_s_barrier();
    QUAD(av1, bv0, 4, 0);
    __builtin_amdgcn_s_barrier();
    readB(cur, 1, bv1);
    __builtin_amdgcn_s_barrier();
    QUAD(av1, bv1, 4, 2);
    __builtin_amdgcn_s_barrier();
    asm volatile("s_waitcnt vmcnt(0)" ::: "memory");
    __builtin_amdgcn_s_barrier();
    QUAD(av0, bv1, 0, 2);
    __builtin_amdgcn_s_barrier();
  }
  // t = NT-1: all data resident, no stages -> no barriers needed
  {
    const int cur = (NT - 1) & 1;
    readA(cur, 0, av0);
    readB(cur, 0, bv0);
    QUAD(av0, bv0, 0, 0);
    readA(cur, 1, av1);
    QUAD(av1, bv0, 4, 0);
    readB(cur, 1, bv1);
    QUAD(av1, bv1, 4, 2);
    QUAD(av0, bv1, 0, 2);
  }
#undef QUAD

  // epilogue: D layout col = lane&15, row = (lane>>4)*4 + j
#pragma unroll
  for (int mi = 0; mi < 8; ++mi) {
#pragma unroll
    for (int ni = 0; ni < 4; ++ni) {
      size_t row = m0 + wm * 128 + mi * 16 + q * 4;
      size_t col = n0 + wn * 64 + ni * 16 + r16;
#pragma unroll
      for (int j = 0; j < 4; ++j)
        C[(row + j) * Ndim + col] = f2bf(acc[mi][ni][j]);
    }
  }
}

// ---------- tail: bias + group LN + gates + c LN + outputs ----------
__global__ __launch_bounds__(256)
void tail_kernel(const unsigned short* __restrict__ Cc, const float* __restrict__ cin,
                 const float* __restrict__ bias, const float* __restrict__ gamma,
                 const float* __restrict__ beta, const float* __restrict__ cg,
                 const float* __restrict__ cb, float* __restrict__ out) {
  int lane = threadIdx.x & 63;
  int wid = threadIdx.x >> 6;
  int row = blockIdx.x * 4 + wid;     // one wave per row
  const int base = lane * 16;         // 16 columns per lane

  // c values
  const float4* cp = (const float4*)(cin + (size_t)row * Hdim + base);
  float4 c0 = cp[0], c1 = cp[1], c2 = cp[2], c3 = cp[3];
  float cv[16] = {c0.x, c0.y, c0.z, c0.w, c1.x, c1.y, c1.z, c1.w,
                  c2.x, c2.y, c2.z, c2.w, c3.x, c3.y, c3.z, c3.w};

  float accv[16];   // running sig(i)*tanh(j), then new_c
  float ov[16];     // sig(o)

#pragma unroll
  for (int g = 0; g < 4; ++g) {
    const int4* pp = (const int4*)(Cc + (size_t)row * Ndim + g * Hdim + base);
    int4 u0 = pp[0], u1 = pp[1];
    float vals[16];
    {
      int uu[8] = {u0.x, u0.y, u0.z, u0.w, u1.x, u1.y, u1.z, u1.w};
#pragma unroll
      for (int i = 0; i < 8; ++i) {
        vals[2 * i]     = bf2f((unsigned short)(uu[i] & 0xffff));
        vals[2 * i + 1] = bf2f((unsigned short)(((unsigned)uu[i]) >> 16));
      }
    }
    const float* bp = bias + g * Hdim + base;
#pragma unroll
    for (int t = 0; t < 16; ++t) vals[t] += bp[t];
    float s = 0.f, ss = 0.f;
#pragma unroll
    for (int t = 0; t < 16; ++t) { s += vals[t]; ss += vals[t] * vals[t]; }
#pragma unroll
    for (int off = 32; off; off >>= 1) { s += __shfl_xor(s, off); ss += __shfl_xor(ss, off); }
    float mean = s * (1.f / 1024.f);
    float rstd = rsqrtf(ss * (1.f / 1024.f) - mean * mean + 1e-3f);
    const float* gp = gamma + g * Hdim + base;
    const float* bb = beta + g * Hdim + base;
    if (g == 0) {
#pragma unroll
      for (int t = 0; t < 16; ++t)
        accv[t] = sigmoidf_((vals[t] - mean) * rstd * gp[t] + bb[t]);
    } else if (g == 1) {
#pragma unroll
      for (int t = 0; t < 16; ++t)
        accv[t] *= tanhf_((vals[t] - mean) * rstd * gp[t] + bb[t]);
    } else if (g == 2) {
#pragma unroll
      for (int t = 0; t < 16; ++t)
        accv[t] = cv[t] * sigmoidf_((vals[t] - mean) * rstd * gp[t] + bb[t] + 1.f) + accv[t];
    } else {
#pragma unroll
      for (int t = 0; t < 16; ++t)
        ov[t] = sigmoidf_((vals[t] - mean) * rstd * gp[t] + bb[t]);
    }
  }

  // LN over new_c (accv)
  float s = 0.f, ss = 0.f;
#pragma unroll
  for (int t = 0; t < 16; ++t) { s += accv[t]; ss += accv[t] * accv[t]; }
#pragma unroll
  for (int off = 32; off; off >>= 1) { s += __shfl_xor(s, off); ss += __shfl_xor(ss, off); }
  float mean = s * (1.f / 1024.f);
  float rstd = rsqrtf(ss * (1.f / 1024.f) - mean * mean + 1e-3f);

  const float* cgp = cg + base;
  const float* cbp = cb + base;
  float hv[16];
#pragma unroll
  for (int t = 0; t < 16; ++t) {
    float cl = (accv[t] - mean) * rstd * cgp[t] + cbp[t];
    hv[t] = tanhf_(cl) * ov[t];
  }

  float4* oh = (float4*)(out + (size_t)row * Hdim + base);
  float4* oc = (float4*)(out + (size_t)Mdim * Hdim + (size_t)row * Hdim + base);
#pragma unroll
  for (int v = 0; v < 4; ++v) {
    oh[v] = make_float4(hv[4 * v], hv[4 * v + 1], hv[4 * v + 2], hv[4 * v + 3]);
    oc[v] = make_float4(accv[4 * v], accv[4 * v + 1], accv[4 * v + 2], accv[4 * v + 3]);
  }
}

extern "C" void kernel_launch(void* const* d_in, const int* in_sizes, int n_in,
                              void* d_out, int out_size, void* d_ws, size_t ws_size,
                              hipStream_t stream) {
  const float* x    = (const float*)d_in[0];
  const float* c    = (const float*)d_in[1];
  const float* h    = (const float*)d_in[2];
  const float* Wxh  = (const float*)d_in[3];
  const float* Whh  = (const float*)d_in[4];
  const float* bias = (const float*)d_in[5];
  const float* lng  = (const float*)d_in[6];
  const float* lnb  = (const float*)d_in[7];
  const float* cg   = (const float*)d_in[8];
  const float* cb   = (const float*)d_in[9];
  float* out = (float*)d_out;

  // workspace layout (needs 117,440,512 B):
  unsigned short* Abf = (unsigned short*)d_ws;                  // 8192*2048 bf16 = 32 MiB
  unsigned short* Wt  = Abf + (size_t)Mdim * Kdim;              // 4096*2048 bf16 = 16 MiB
  unsigned short* Cc  = Wt  + (size_t)Ndim * Kdim;              // 8192*4096 bf16 = 64 MiB

  conv_a_kernel<<<8192, 256, 0, stream>>>(x, h, Abf);
  conv_w_kernel<<<dim3(Kdim / 32, Ndim / 32), 256, 0, stream>>>(Wxh, Whh, Wt);
  gemm_kernel<<<(Mdim / BM) * (Ndim / BN), 512, 0, stream>>>(Abf, Wt, Cc);
  tail_kernel<<<Mdim / 4, 256, 0, stream>>>(Cc, c, bias, lng, lnb, cg, cb, out);
}